// Round 3
// baseline (1866.946 us; speedup 1.0000x reference)
//
#include <hip/hip_runtime.h>
#include <utility>

// SICE head for MI355X (gfx950) — round 3.
// R3: mm_ns/k_gram are LDS-free & barrier-free (MFMA fragments loaded
// directly from global; wave reads 16 rows x 64B = full lines; operands
// L2-resident per XCD); k_xt eliminated (k_conv stages B straight from f32 x
// with lane-coalesced loads); k_conv LDS stride 56 halves (112B: 16B-aligned
// b128, 2-way max conflicts), tile 128x64, grid 832.

typedef unsigned short u16;
typedef __attribute__((ext_vector_type(8))) __bf16 bf16x8;
typedef __attribute__((ext_vector_type(8))) _Float16 f16x8;
typedef __attribute__((ext_vector_type(4))) float f32x4;

#define DEV __device__ __forceinline__

DEV u16 f2bf(float f) {
  unsigned x = __float_as_uint(f);
  x += 0x7fffu + ((x >> 16) & 1u);
  return (u16)(x >> 16);
}
DEV float bf2f(u16 h) { return __uint_as_float(((unsigned)h) << 16); }

// sb float-index layout
#define SB_SUM   0
#define SB_SSQ   256
#define SB_IJ    512
#define SB_TRC   768
#define SB_TR2   800
#define SB_TR3   832
#define SB_TRL   864
#define SB_DEN   896
#define SB_IJSUM 928

// ---------------- prep: w -> fp16, init sb ----------------
__global__ __launch_bounds__(256) void k_prep(const float* __restrict__ w,
                                              const float* __restrict__ jitter,
                                              _Float16* __restrict__ w_half,
                                              float* __restrict__ sb) {
  int gid = blockIdx.x * 256 + threadIdx.x;
  if (gid < 256 * 2048) w_half[gid] = (_Float16)w[gid];
  if (blockIdx.x == 0) {
    int t = threadIdx.x;
    sb[SB_SUM + t] = 0.f;
    sb[SB_SSQ + t] = 0.f;
    float ij = 1e-10f + 1e-9f * jitter[t];
    sb[SB_IJ + t] = ij;
    if (t < 160) sb[SB_TRC + t] = 0.f;
    __shared__ float red[256];
    red[t] = ij; __syncthreads();
    for (int off = 128; off > 0; off >>= 1) {
      if (t < off) red[t] += red[t + off];
      __syncthreads();
    }
    if (t == 0) sb[SB_IJSUM] = red[0];
  }
}

// ---------------- conv: y[b,d,hw] = w@x (fp16 out) + BN stats ----------------
// grid 832 = 26 (mt*13+ht) x 32 b. Tile 128(d) x 64(hw), BK=32, stride-56 LDS.
// B staged directly from f32 x: wave = 64 consecutive hw (coalesced), c = wv*8+j.
__global__ __launch_bounds__(256) void k_conv(const _Float16* __restrict__ w_half,
                                              const float* __restrict__ x,
                                              _Float16* __restrict__ y,
                                              float* __restrict__ sb) {
  int xb = blockIdx.x;
  int b = xb & 31;
  int rest = xb >> 5;              // 0..25
  int mt = rest / 13, ht = rest % 13;
  int hw0 = ht * 64;
  int t = threadIdx.x;
  int wv = t >> 6, lane = t & 63, m = lane & 15, quad = lane >> 4;
  __shared__ _Float16 lsA[128 * 56];
  __shared__ _Float16 lsB[64 * 56];
  f32x4 acc[4][2];
#pragma unroll
  for (int i = 0; i < 4; ++i)
#pragma unroll
    for (int j = 0; j < 2; ++j) acc[i][j] = (f32x4){0.f, 0.f, 0.f, 0.f};
  int rowA = t >> 2, segA = t & 3;
  const _Float16* wp = w_half + ((size_t)(mt * 128 + rowA)) * 2048 + segA * 8;
  int hwB = lane;                  // 0..63 consecutive per wave -> coalesced
  int cg = wv;                     // c-group of 8
  bool okB = (hw0 + hwB) < 784;
  const float* xp = x + ((size_t)b * 2048 + cg * 8) * 784 + hw0 + hwB;
  uint4 ra0, ra1;
  float rb[8];
  ra0 = *(const uint4*)(wp);
  ra1 = *(const uint4*)(wp + 64 * 2048);
#pragma unroll
  for (int j = 0; j < 8; ++j) rb[j] = okB ? xp[(size_t)j * 784] : 0.f;
  for (int kc = 0; kc < 64; ++kc) {
    int lo = rowA * 56 + segA * 8;
    *(uint4*)&lsA[lo] = ra0;
    *(uint4*)&lsA[lo + 64 * 56] = ra1;
    {
      union { f16x8 h; uint4 u; } pk;
#pragma unroll
      for (int j = 0; j < 8; ++j) pk.h[j] = (_Float16)rb[j];
      *(uint4*)&lsB[hwB * 56 + cg * 8] = pk.u;
    }
    __syncthreads();
    if (kc < 63) {
      int k0 = (kc + 1) * 32;
      ra0 = *(const uint4*)(wp + k0);
      ra1 = *(const uint4*)(wp + 64 * 2048 + k0);
#pragma unroll
      for (int j = 0; j < 8; ++j)
        rb[j] = okB ? xp[((size_t)k0 + j) * 784] : 0.f;
    }
    int wr = (wv >> 1) * 64, wc = (wv & 1) * 32;
    f16x8 af[4], bfg[2];
#pragma unroll
    for (int i = 0; i < 4; ++i)
      af[i] = *(const f16x8*)&lsA[(wr + i * 16 + m) * 56 + quad * 8];
#pragma unroll
    for (int j = 0; j < 2; ++j)
      bfg[j] = *(const f16x8*)&lsB[(wc + j * 16 + m) * 56 + quad * 8];
#pragma unroll
    for (int i = 0; i < 4; ++i)
#pragma unroll
      for (int j = 0; j < 2; ++j)
        acc[i][j] = __builtin_amdgcn_mfma_f32_16x16x32_f16(af[i], bfg[j], acc[i][j], 0, 0, 0);
    __syncthreads();
  }
  int wr = (wv >> 1) * 64, wc = (wv & 1) * 32;
  float* sum = sb + SB_SUM;
  float* ssq = sb + SB_SSQ;
#pragma unroll
  for (int i = 0; i < 4; ++i) {
#pragma unroll
    for (int r = 0; r < 4; ++r) {
      float s = 0.f, q = 0.f;
#pragma unroll
      for (int j = 0; j < 2; ++j) {
        float v = acc[i][j][r];
        s += v; q += v * v;
      }
      s += __shfl_xor(s, 1); s += __shfl_xor(s, 2);
      s += __shfl_xor(s, 4); s += __shfl_xor(s, 8);
      q += __shfl_xor(q, 1); q += __shfl_xor(q, 2);
      q += __shfl_xor(q, 4); q += __shfl_xor(q, 8);
      if (m == 0) {
        int R = mt * 128 + wr + i * 16 + quad * 4 + r;
        atomicAdd(&sum[R], s);
        atomicAdd(&ssq[R], q);
      }
    }
  }
#pragma unroll
  for (int i = 0; i < 4; ++i)
#pragma unroll
    for (int j = 0; j < 2; ++j)
#pragma unroll
      for (int r = 0; r < 4; ++r) {
        int R = mt * 128 + wr + i * 16 + quad * 4 + r;
        int hwc = hw0 + wc + j * 16 + m;
        if (hwc < 784) y[((size_t)b * 256 + R) * 784 + hwc] = (_Float16)acc[i][j][r];
      }
}

// ---------------- BN finalize+apply + relu + row-center -> yc fp16 --------
__global__ __launch_bounds__(256) void k_bnapply(const _Float16* __restrict__ y,
                                                 const float* __restrict__ gamma,
                                                 const float* __restrict__ beta,
                                                 const float* __restrict__ sb,
                                                 _Float16* __restrict__ yc) {
  int xb = blockIdx.x;
  int d = xb >> 5, b = xb & 31, t = threadIdx.x;
  float mu = sb[SB_SUM + d] * (1.0f / 25088.0f);
  float var = sb[SB_SSQ + d] * (1.0f / 25088.0f) - mu * mu;
  float sc = gamma[d] / sqrtf(var + 1e-5f);
  float sh = beta[d] - mu * sc;
  const _Float16* row = y + ((size_t)b * 256 + d) * 784;
  float v[4];
  float s = 0.f;
#pragma unroll
  for (int i = 0; i < 4; ++i) {
    int idx = t + i * 256;
    float u = 0.f;
    if (idx < 784) u = fmaxf((float)row[idx] * sc + sh, 0.f);
    v[i] = u; s += u;
  }
  __shared__ float red[256];
  red[t] = s; __syncthreads();
  for (int off = 128; off > 0; off >>= 1) {
    if (t < off) red[t] += red[t + off];
    __syncthreads();
  }
  float mean = red[0] * (1.0f / 784.0f);
  _Float16* out = yc + ((size_t)b * 256 + d) * 800;
#pragma unroll
  for (int i = 0; i < 4; ++i) {
    int idx = t + i * 256;
    if (idx < 784) out[idx] = (_Float16)(v[i] - mean);
  }
  if (t < 16) out[784 + t] = (_Float16)0.f;
}

// ---------------- gram: C = yc@yc^T/784 — LDS-free, barrier-free ----------
// grid 1024 = 32 tiles(64x32) x 32 b.
__global__ __launch_bounds__(256) void k_gram(const _Float16* __restrict__ yc,
                                              float* __restrict__ C,
                                              float* __restrict__ sb) {
  int xb = blockIdx.x;
  int b = xb & 31, rest = xb >> 5;
  int tr = rest >> 3, tc = rest & 7;
  int lane = threadIdx.x & 63, wv = threadIdx.x >> 6;
  int m = lane & 15, q = lane >> 4;
  int wr = tr * 64 + (wv >> 1) * 32;
  int wc = tc * 32 + (wv & 1) * 16;
  const _Float16* base = yc + (size_t)b * 256 * 800;
  const _Float16* pa0 = base + (size_t)(wr + m) * 800 + q * 8;
  const _Float16* pa1 = pa0 + 16 * 800;
  const _Float16* pb = base + (size_t)(wc + m) * 800 + q * 8;
  f32x4 acc[2];
  acc[0] = (f32x4){0.f, 0.f, 0.f, 0.f};
  acc[1] = (f32x4){0.f, 0.f, 0.f, 0.f};
  f16x8 ra0 = *(const f16x8*)pa0;
  f16x8 ra1 = *(const f16x8*)pa1;
  f16x8 rb = *(const f16x8*)pb;
  for (int ks = 0; ks < 25; ++ks) {
    f16x8 ca0 = ra0, ca1 = ra1, cb = rb;
    if (ks < 24) {
      int k0 = (ks + 1) * 32;
      ra0 = *(const f16x8*)(pa0 + k0);
      ra1 = *(const f16x8*)(pa1 + k0);
      rb = *(const f16x8*)(pb + k0);
    }
    acc[0] = __builtin_amdgcn_mfma_f32_16x16x32_f16(ca0, cb, acc[0], 0, 0, 0);
    acc[1] = __builtin_amdgcn_mfma_f32_16x16x32_f16(ca1, cb, acc[1], 0, 0, 0);
  }
  const float inv = 1.0f / 784.0f;
#pragma unroll
  for (int i = 0; i < 2; ++i)
#pragma unroll
    for (int r = 0; r < 4; ++r) {
      int R = wr + i * 16 + q * 4 + r;
      int Cc = wc + m;
      float v = acc[i][r] * inv;
      C[((size_t)b * 256 + R) * 256 + Cc] = v;
      if (R == Cc) atomicAdd(&sb[SB_TRC + b], v);
    }
}

// ---------------- prep A and ZY (split bf16); mode0 also writes symC ------
__global__ __launch_bounds__(256) void k_prepAZY(const float* __restrict__ src,
                                                 float* __restrict__ symC,
                                                 u16* __restrict__ Ah, u16* __restrict__ Al,
                                                 u16* __restrict__ ZYh, u16* __restrict__ ZYl,
                                                 float* __restrict__ sb, int slot, int mode) {
  int xb = blockIdx.x;
  int i = xb >> 5, b = xb & 31, j = threadIdx.x;
  float trv = (mode == 0) ? 1.0f : sb[slot + b];
  float denom = trv + sb[SB_IJSUM];
  if (i == 0 && j == 0) sb[SB_DEN + b] = denom;
  size_t idx = ((size_t)b * 256 + i) * 256 + j;
  float v;
  if (mode == 0) {
    float trC = sb[SB_TRC + b];
    float vij = src[idx] / trC;
    float vji = src[((size_t)b * 256 + j) * 256 + i] / trC;
    symC[idx] = 0.5f * (vij + vji);
    v = vij;
  } else {
    v = src[idx];
  }
  if (i == j) v += sb[SB_IJ + i];
  float A = v / denom;
  u16 h = f2bf(A);
  Ah[idx] = h; Al[idx] = f2bf(A - bf2f(h));
  float zy = 0.5f * ((i == j ? 3.0f : 0.0f) - A);
  h = f2bf(zy);
  ZYh[idx] = h; ZYl[idx] = f2bf(zy - bf2f(h));
}

// ---------------- batched split-bf16 matmul — LDS-free, barrier-free ------
// C[i][j] = sum_k A[i][k]*B[j][k] (B symmetric => A@B).
// Tile 64x32, grid 1024 (single) / 2048 (dual).
// emode: 0 plain->split, 1 ZY=0.5(3I-C)->split, 2 C*rsqrt(den)->split, 3 ->f32
struct MMArgs {
  const u16* Ah; const u16* Al; const u16* Bh; const u16* Bl;
  u16* Oh; u16* Ol; float* Of; float* tr; int emode;
};

__global__ __launch_bounds__(256) void mm_ns(MMArgs g0, MMArgs g1,
                                             const float* __restrict__ sb) {
  int xb = blockIdx.x;
  int b = xb & 31;
  int rest = xb >> 5;
  MMArgs g = (rest < 32) ? g0 : g1;
  int tile = rest & 31;
  int tr = tile >> 3, tc = tile & 7;
  int lane = threadIdx.x & 63, wv = threadIdx.x >> 6;
  int m = lane & 15, q = lane >> 4;
  int wr = tr * 64 + (wv >> 1) * 32;
  int wc = tc * 32 + (wv & 1) * 16;
  size_t mb = (size_t)b * 65536;
  size_t a0 = mb + (size_t)(wr + m) * 256 + q * 8;
  size_t a1 = a0 + 16 * 256;
  size_t bo = mb + (size_t)(wc + m) * 256 + q * 8;
  f32x4 acc[2];
  acc[0] = (f32x4){0.f, 0.f, 0.f, 0.f};
  acc[1] = (f32x4){0.f, 0.f, 0.f, 0.f};
  bf16x8 ra0h = *(const bf16x8*)(g.Ah + a0);
  bf16x8 ra1h = *(const bf16x8*)(g.Ah + a1);
  bf16x8 ra0l = *(const bf16x8*)(g.Al + a0);
  bf16x8 ra1l = *(const bf16x8*)(g.Al + a1);
  bf16x8 rbh = *(const bf16x8*)(g.Bh + bo);
  bf16x8 rbl = *(const bf16x8*)(g.Bl + bo);
  for (int ks = 0; ks < 8; ++ks) {
    bf16x8 ca0h = ra0h, ca1h = ra1h, ca0l = ra0l, ca1l = ra1l, cbh = rbh, cbl = rbl;
    if (ks < 7) {
      int k0 = (ks + 1) * 32;
      ra0h = *(const bf16x8*)(g.Ah + a0 + k0);
      ra1h = *(const bf16x8*)(g.Ah + a1 + k0);
      ra0l = *(const bf16x8*)(g.Al + a0 + k0);
      ra1l = *(const bf16x8*)(g.Al + a1 + k0);
      rbh = *(const bf16x8*)(g.Bh + bo + k0);
      rbl = *(const bf16x8*)(g.Bl + bo + k0);
    }
    acc[0] = __builtin_amdgcn_mfma_f32_16x16x32_bf16(ca0h, cbh, acc[0], 0, 0, 0);
    acc[0] = __builtin_amdgcn_mfma_f32_16x16x32_bf16(ca0h, cbl, acc[0], 0, 0, 0);
    acc[0] = __builtin_amdgcn_mfma_f32_16x16x32_bf16(ca0l, cbh, acc[0], 0, 0, 0);
    acc[1] = __builtin_amdgcn_mfma_f32_16x16x32_bf16(ca1h, cbh, acc[1], 0, 0, 0);
    acc[1] = __builtin_amdgcn_mfma_f32_16x16x32_bf16(ca1h, cbl, acc[1], 0, 0, 0);
    acc[1] = __builtin_amdgcn_mfma_f32_16x16x32_bf16(ca1l, cbh, acc[1], 0, 0, 0);
  }
  float scl = 1.0f;
  if (g.emode == 2) scl = 1.0f / sqrtf(sb[SB_DEN + b]);
#pragma unroll
  for (int i = 0; i < 2; ++i)
#pragma unroll
    for (int r = 0; r < 4; ++r) {
      int R = wr + i * 16 + q * 4 + r;
      int Cc = wc + m;
      float v = acc[i][r];
      if (g.emode == 1) v = 0.5f * ((R == Cc ? 3.0f : 0.0f) - v);
      else if (g.emode == 2) v = v * scl;
      size_t oidx = mb + (size_t)R * 256 + Cc;
      if (g.emode == 3) {
        g.Of[oidx] = v;
        if (R == Cc && g.tr) atomicAdd(g.tr + b, v);
      } else {
        u16 h = f2bf(v);
        g.Oh[oidx] = h;
        g.Ol[oidx] = f2bf(v - bf2f(h));
      }
    }
}

// ---------------- SICE elementwise update, tile-symmetric ----------------
__global__ __launch_bounds__(256) void k_sice(const float* __restrict__ LLT,
                                              const float* __restrict__ P,
                                              const float* __restrict__ symC,
                                              float* __restrict__ out,
                                              float* __restrict__ sb, int slot,
                                              float dec) {
  int xb = blockIdx.x;
  int b = xb & 31, p = xb >> 5;
  const int TRt[10] = {0, 0, 0, 0, 1, 1, 1, 2, 2, 3};
  const int TCt[10] = {0, 1, 2, 3, 1, 2, 3, 2, 3, 3};
  int tr = TRt[p], tc = TCt[p];
  __shared__ float ft[64][65];
  __shared__ float ot[64][65];
  int t = threadIdx.x;
  size_t base = (size_t)b * 65536;
#pragma unroll 4
  for (int it = 0; it < 16; ++it) {
    int idx = it * 256 + t;
    int r = idx >> 6, c = idx & 63;
    size_t o = base + (size_t)(tc * 64 + r) * 256 + tr * 64 + c;
    float L = LLT[o];
    float g = symC[o] - P[o];
    float f = fmaxf(fmaxf(L, 0.f) - dec * (g + 0.07f), 0.f) -
              fmaxf(fmaxf(-L, 0.f) - dec * (-g + 0.07f), 0.f);
    ft[r][c] = f;
  }
  __syncthreads();
  float tsum = 0.f;
#pragma unroll 4
  for (int it = 0; it < 16; ++it) {
    int idx = it * 256 + t;
    int r = idx >> 6, c = idx & 63;
    size_t o = base + (size_t)(tr * 64 + r) * 256 + tc * 64 + c;
    float L = LLT[o];
    float g = symC[o] - P[o];
    float f = fmaxf(fmaxf(L, 0.f) - dec * (g + 0.07f), 0.f) -
              fmaxf(fmaxf(-L, 0.f) - dec * (-g + 0.07f), 0.f);
    float val = 0.5f * (f + ft[c][r]);
    out[o] = val;
    ot[r][c] = val;
    if (tr == tc && r == c) tsum += val;
  }
  if (tr == tc) {
    if (tsum != 0.f) atomicAdd(&sb[slot + b], tsum);
  } else {
    __syncthreads();
#pragma unroll 4
    for (int it = 0; it < 16; ++it) {
      int idx = it * 256 + t;
      int r = idx >> 6, c = idx & 63;
      size_t o = base + (size_t)(tc * 64 + r) * 256 + tr * 64 + c;
      out[o] = ot[c][r];
    }
  }
}

// ---------------- triu-vec output ----------------
__global__ __launch_bounds__(256) void k_out(const float* __restrict__ LLT,
                                             const float* __restrict__ sb,
                                             float* __restrict__ out) {
  int xb = blockIdx.x;
  int i = xb >> 5, b = xb & 31, j = threadIdx.x;
  if (j < i) return;
  float inv = 1.0f / sqrtf(sb[SB_TRL + b]);
  int tl = i * 256 - (i * (i - 1)) / 2 + (j - i);
  out[(size_t)b * 32896 + tl] = LLT[((size_t)b * 256 + i) * 256 + j] * inv;
}

extern "C" void kernel_launch(void* const* d_in, const int* in_sizes, int n_in,
                              void* d_out, int out_size, void* d_ws, size_t ws_size,
                              hipStream_t stream) {
  const float* x = (const float*)d_in[0];
  const float* w = (const float*)d_in[1];
  const float* gamma = (const float*)d_in[2];
  const float* beta = (const float*)d_in[3];
  const float* jitter = (const float*)d_in[4];
  char* ws = (char*)d_ws;

  _Float16* w_half = (_Float16*)(ws + 0);            // 1 MB
  float* sb = (float*)(ws + (1 << 20));              // 4 KB
  _Float16* y = (_Float16*)(ws + (2 << 20));         // 12.85 MB
  _Float16* yc = (_Float16*)(ws + (16 << 20));       // 13.1 MB
  char* ov = ws + (32 << 20);
  float* Craw = (float*)(ov + 0);
  float* symC = (float*)(ov + 8388608);
  float* LLTa = (float*)(ov + 16777216);
  float* P = (float*)(ov + 25165824);
  float* LLTb = (float*)(ov + 33554432);
  u16* bf[12];
  for (int i = 0; i < 12; ++i) bf[i] = (u16*)(ov + 41943040 + (size_t)i * 4194304);

  k_prep<<<2048, 256, 0, stream>>>(w, jitter, w_half, sb);
  k_conv<<<832, 256, 0, stream>>>(w_half, x, y, sb);
  k_bnapply<<<8192, 256, 0, stream>>>(y, gamma, beta, sb, yc);
  k_gram<<<1024, 256, 0, stream>>>(yc, Craw, sb);

  auto run_ns = [&](const float* src, int mode, int slot_in, float* Pout,
                    float* tr_out) {
    k_prepAZY<<<8192, 256, 0, stream>>>(src, symC, bf[0], bf[1], bf[2], bf[3], sb, slot_in, mode);
    u16 *Ah = bf[0], *Al = bf[1], *ZYh = bf[2], *ZYl = bf[3];
    u16 *Yh = bf[4], *Yl = bf[5], *Z2h = bf[6], *Z2l = bf[7];
    u16 *Th = bf[8], *Tl = bf[9], *zzh = bf[10], *zzl = bf[11];
    MMArgs m1{Ah, Al, ZYh, ZYl, Yh, Yl, nullptr, nullptr, 0};
    mm_ns<<<1024, 256, 0, stream>>>(m1, m1, sb);
    u16 *Ych = Yh, *Ycl = Yl, *Yah = Ah, *Yal = Al;
    u16 *Zch = ZYh, *Zcl = ZYl, *Zah = Z2h, *Zal = Z2l;
    for (int it = 0; it < 5; ++it) {
      MMArgs mt{Zch, Zcl, Ych, Ycl, Th, Tl, nullptr, nullptr, 1};
      mm_ns<<<1024, 256, 0, stream>>>(mt, mt, sb);
      MMArgs my{Ych, Ycl, Th, Tl, Yah, Yal, nullptr, nullptr, 0};
      MMArgs mz{Th, Tl, Zch, Zcl, Zah, Zal, nullptr, nullptr, 0};
      mm_ns<<<2048, 256, 0, stream>>>(my, mz, sb);
      std::swap(Ych, Yah); std::swap(Ycl, Yal);
      std::swap(Zch, Zah); std::swap(Zcl, Zal);
    }
    MMArgs mt6{Zch, Zcl, Ych, Ycl, Th, Tl, nullptr, nullptr, 1};
    mm_ns<<<1024, 256, 0, stream>>>(mt6, mt6, sb);
    MMArgs mz7{Th, Tl, Zch, Zcl, zzh, zzl, nullptr, nullptr, 2};
    mm_ns<<<1024, 256, 0, stream>>>(mz7, mz7, sb);
    MMArgs mzz{zzh, zzl, zzh, zzl, nullptr, nullptr, Pout, tr_out, 3};
    mm_ns<<<1024, 256, 0, stream>>>(mzz, mzz, sb);
  };

  run_ns(Craw, 0, 0, LLTa, sb + SB_TR2);   // LLT init (trace -> TR2)
  run_ns(LLTa, 1, SB_TR2, P, nullptr);     // SICE i=0
  k_sice<<<320, 256, 0, stream>>>(LLTa, P, symC, LLTb, sb, SB_TR3, 5.0f);
  run_ns(LLTb, 1, SB_TR3, P, nullptr);     // SICE i=1
  k_sice<<<320, 256, 0, stream>>>(LLTb, P, symC, LLTa, sb, SB_TRL, 2.5f);
  // SICE i=2: dec=0 -> provable no-op

  k_out<<<8192, 256, 0, stream>>>(LLTa, sb, (float*)d_out);
}

// Round 4
// 1050.512 us; speedup vs baseline: 1.7772x; 1.7772x over previous
//
#include <hip/hip_runtime.h>
#include <utility>

// SICE head for MI355X (gfx950) — round 4.
// R4: all GEMMs use double-buffered LDS (ONE barrier per K-step) + register
// prefetch; mm_ns tile 32x64 (grid 1024/2048 = 4-8 WG/CU) with LDS reuse
// (R3's LDS-free version tripled L2/LLC traffic -> 32us each; R2's 2-barrier
// version latency-stalled at 2 WG/CU). k_conv tile 128x64, BK=32, dbuf,
// stages B straight from f32 x (LLC-resident). Batch index kept in low 5
// bits of blockIdx everywhere -> XCD = b%8 L2 locality.

typedef unsigned short u16;
typedef __attribute__((ext_vector_type(8))) __bf16 bf16x8;
typedef __attribute__((ext_vector_type(8))) _Float16 f16x8;
typedef __attribute__((ext_vector_type(4))) float f32x4;

#define DEV __device__ __forceinline__

DEV u16 f2bf(float f) {
  unsigned x = __float_as_uint(f);
  x += 0x7fffu + ((x >> 16) & 1u);
  return (u16)(x >> 16);
}
DEV float bf2f(u16 h) { return __uint_as_float(((unsigned)h) << 16); }

// sb float-index layout
#define SB_SUM   0
#define SB_SSQ   256
#define SB_IJ    512
#define SB_TRC   768
#define SB_TR2   800
#define SB_TR3   832
#define SB_TRL   864
#define SB_DEN   896
#define SB_IJSUM 928

// ---------------- prep: w -> fp16, init sb ----------------
__global__ __launch_bounds__(256) void k_prep(const float* __restrict__ w,
                                              const float* __restrict__ jitter,
                                              _Float16* __restrict__ w_half,
                                              float* __restrict__ sb) {
  int gid = blockIdx.x * 256 + threadIdx.x;
  if (gid < 256 * 2048) w_half[gid] = (_Float16)w[gid];
  if (blockIdx.x == 0) {
    int t = threadIdx.x;
    sb[SB_SUM + t] = 0.f;
    sb[SB_SSQ + t] = 0.f;
    float ij = 1e-10f + 1e-9f * jitter[t];
    sb[SB_IJ + t] = ij;
    if (t < 160) sb[SB_TRC + t] = 0.f;
    __shared__ float red[256];
    red[t] = ij; __syncthreads();
    for (int off = 128; off > 0; off >>= 1) {
      if (t < off) red[t] += red[t + off];
      __syncthreads();
    }
    if (t == 0) sb[SB_IJSUM] = red[0];
  }
}

// ---------------- conv: y[b,d,hw] = w@x (fp16 out) + BN stats ----------------
// grid 832 = 26 (mt*13+ht) x 32 b. Tile 128(d) x 64(hw), BK=32, dbuf LDS.
__global__ __launch_bounds__(256) void k_conv(const _Float16* __restrict__ w_half,
                                              const float* __restrict__ x,
                                              _Float16* __restrict__ y,
                                              float* __restrict__ sb) {
  int xb = blockIdx.x;
  int b = xb & 31;
  int rest = xb >> 5;              // 0..25
  int mt = rest / 13, ht = rest % 13;
  int hw0 = ht * 64;
  int t = threadIdx.x;
  int wv = t >> 6, lane = t & 63, m = lane & 15, quad = lane >> 4;
  __shared__ _Float16 lsA[2][128 * 40];
  __shared__ _Float16 lsB[2][64 * 40];
  f32x4 acc[4][2];
#pragma unroll
  for (int i = 0; i < 4; ++i)
#pragma unroll
    for (int j = 0; j < 2; ++j) acc[i][j] = (f32x4){0.f, 0.f, 0.f, 0.f};
  // A staging: row = t&127, half = t>>7 -> two uint4 at k = half*16 + {0,8}
  int rowA = t & 127, halfA = t >> 7;
  const _Float16* wp = w_half + ((size_t)(mt * 128 + rowA)) * 2048 + halfA * 16;
  // B staging: hw = t&63, cg = t>>6 -> 8 dword loads c = cg*8+j
  int hwB = t & 63, cg = t >> 6;
  bool okB = (hw0 + hwB) < 784;
  const float* xp = x + ((size_t)b * 2048 + cg * 8) * 784 + hw0 + hwB;
  uint4 ra0, ra1;
  float rb[8];
  ra0 = *(const uint4*)(wp);
  ra1 = *(const uint4*)(wp + 8);
#pragma unroll
  for (int j = 0; j < 8; ++j) rb[j] = okB ? xp[(size_t)j * 784] : 0.f;
  int wr = (wv >> 1) * 64, wc = (wv & 1) * 32;
  for (int kc = 0; kc < 64; ++kc) {
    int buf = kc & 1;
    int loA = rowA * 40 + halfA * 16;
    *(uint4*)&lsA[buf][loA] = ra0;
    *(uint4*)&lsA[buf][loA + 8] = ra1;
    {
      union { f16x8 h; uint4 u; } pk;
#pragma unroll
      for (int j = 0; j < 8; ++j) pk.h[j] = (_Float16)rb[j];
      *(uint4*)&lsB[buf][hwB * 40 + cg * 8] = pk.u;
    }
    if (kc < 63) {
      int k0 = (kc + 1) * 32;
      ra0 = *(const uint4*)(wp + k0);
      ra1 = *(const uint4*)(wp + k0 + 8);
#pragma unroll
      for (int j = 0; j < 8; ++j)
        rb[j] = okB ? xp[((size_t)k0 + j) * 784] : 0.f;
    }
    __syncthreads();
    f16x8 af[4], bfg[2];
#pragma unroll
    for (int i = 0; i < 4; ++i)
      af[i] = *(const f16x8*)&lsA[buf][(wr + i * 16 + m) * 40 + quad * 8];
#pragma unroll
    for (int j = 0; j < 2; ++j)
      bfg[j] = *(const f16x8*)&lsB[buf][(wc + j * 16 + m) * 40 + quad * 8];
#pragma unroll
    for (int i = 0; i < 4; ++i)
#pragma unroll
      for (int j = 0; j < 2; ++j)
        acc[i][j] = __builtin_amdgcn_mfma_f32_16x16x32_f16(af[i], bfg[j], acc[i][j], 0, 0, 0);
  }
  float* sum = sb + SB_SUM;
  float* ssq = sb + SB_SSQ;
#pragma unroll
  for (int i = 0; i < 4; ++i) {
#pragma unroll
    for (int r = 0; r < 4; ++r) {
      float s = 0.f, q = 0.f;
#pragma unroll
      for (int j = 0; j < 2; ++j) {
        float v = acc[i][j][r];
        s += v; q += v * v;
      }
      s += __shfl_xor(s, 1); s += __shfl_xor(s, 2);
      s += __shfl_xor(s, 4); s += __shfl_xor(s, 8);
      q += __shfl_xor(q, 1); q += __shfl_xor(q, 2);
      q += __shfl_xor(q, 4); q += __shfl_xor(q, 8);
      if (m == 0) {
        int R = mt * 128 + wr + i * 16 + quad * 4 + r;
        atomicAdd(&sum[R], s);
        atomicAdd(&ssq[R], q);
      }
    }
  }
#pragma unroll
  for (int i = 0; i < 4; ++i)
#pragma unroll
    for (int j = 0; j < 2; ++j)
#pragma unroll
      for (int r = 0; r < 4; ++r) {
        int R = mt * 128 + wr + i * 16 + quad * 4 + r;
        int hwc = hw0 + wc + j * 16 + m;
        if (hwc < 784) y[((size_t)b * 256 + R) * 784 + hwc] = (_Float16)acc[i][j][r];
      }
}

// ---------------- BN finalize+apply + relu + row-center -> yc fp16 --------
__global__ __launch_bounds__(256) void k_bnapply(const _Float16* __restrict__ y,
                                                 const float* __restrict__ gamma,
                                                 const float* __restrict__ beta,
                                                 const float* __restrict__ sb,
                                                 _Float16* __restrict__ yc) {
  int xb = blockIdx.x;
  int d = xb >> 5, b = xb & 31, t = threadIdx.x;
  float mu = sb[SB_SUM + d] * (1.0f / 25088.0f);
  float var = sb[SB_SSQ + d] * (1.0f / 25088.0f) - mu * mu;
  float sc = gamma[d] / sqrtf(var + 1e-5f);
  float sh = beta[d] - mu * sc;
  const _Float16* row = y + ((size_t)b * 256 + d) * 784;
  float v[4];
  float s = 0.f;
#pragma unroll
  for (int i = 0; i < 4; ++i) {
    int idx = t + i * 256;
    float u = 0.f;
    if (idx < 784) u = fmaxf((float)row[idx] * sc + sh, 0.f);
    v[i] = u; s += u;
  }
  __shared__ float red[256];
  red[t] = s; __syncthreads();
  for (int off = 128; off > 0; off >>= 1) {
    if (t < off) red[t] += red[t + off];
    __syncthreads();
  }
  float mean = red[0] * (1.0f / 784.0f);
  _Float16* out = yc + ((size_t)b * 256 + d) * 800;
#pragma unroll
  for (int i = 0; i < 4; ++i) {
    int idx = t + i * 256;
    if (idx < 784) out[idx] = (_Float16)(v[i] - mean);
  }
  if (t < 16) out[784 + t] = (_Float16)0.f;
}

// ---------------- gram: C = yc@yc^T/784 — dbuf LDS, tile 32x64 -----------
// grid 1024 = 32 tiles x 32 b.
__global__ __launch_bounds__(256) void k_gram(const _Float16* __restrict__ yc,
                                              float* __restrict__ C,
                                              float* __restrict__ sb) {
  int xb = blockIdx.x;
  int b = xb & 31, rest = xb >> 5;
  int tr = rest >> 2, tc = rest & 3;   // 8 row-tiles(32) x 4 col-tiles(64)
  int t = threadIdx.x, wv = t >> 6, lane = t & 63, m = lane & 15, quad = lane >> 4;
  __shared__ _Float16 lsA[2][32 * 40];
  __shared__ _Float16 lsB[2][64 * 40];
  f32x4 acc[2];
  acc[0] = (f32x4){0.f, 0.f, 0.f, 0.f};
  acc[1] = (f32x4){0.f, 0.f, 0.f, 0.f};
  int row = t >> 2, seg = t & 3;
  const _Float16* base = yc + (size_t)b * 256 * 800;
  const _Float16* Bp = base + (size_t)(tc * 64 + row) * 800 + seg * 8;
  const _Float16* Ap = base + (size_t)(tr * 32 + row) * 800 + seg * 8;  // row<32 only
  bool doA = row < 32;
  uint4 rB = *(const uint4*)(Bp);
  uint4 rA = doA ? *(const uint4*)(Ap) : (uint4){0, 0, 0, 0};
  int ar = (wv >> 1) * 16, bcl = (wv & 1) * 32;
  for (int ks = 0; ks < 25; ++ks) {
    int buf = ks & 1;
    int lo = row * 40 + seg * 8;
    *(uint4*)&lsB[buf][lo] = rB;
    if (doA) *(uint4*)&lsA[buf][lo] = rA;
    if (ks < 24) {
      int k0 = (ks + 1) * 32;
      rB = *(const uint4*)(Bp + k0);
      if (doA) rA = *(const uint4*)(Ap + k0);
    }
    __syncthreads();
    f16x8 a0 = *(const f16x8*)&lsA[buf][(ar + m) * 40 + quad * 8];
    f16x8 b0 = *(const f16x8*)&lsB[buf][(bcl + m) * 40 + quad * 8];
    f16x8 b1 = *(const f16x8*)&lsB[buf][(bcl + 16 + m) * 40 + quad * 8];
    acc[0] = __builtin_amdgcn_mfma_f32_16x16x32_f16(a0, b0, acc[0], 0, 0, 0);
    acc[1] = __builtin_amdgcn_mfma_f32_16x16x32_f16(a0, b1, acc[1], 0, 0, 0);
  }
  const float inv = 1.0f / 784.0f;
#pragma unroll
  for (int j = 0; j < 2; ++j)
#pragma unroll
    for (int r = 0; r < 4; ++r) {
      int R = tr * 32 + ar + quad * 4 + r;
      int Cc = tc * 64 + bcl + j * 16 + m;
      float v = acc[j][r] * inv;
      C[((size_t)b * 256 + R) * 256 + Cc] = v;
      if (R == Cc) atomicAdd(&sb[SB_TRC + b], v);
    }
}

// ---------------- prep A and ZY (split bf16); mode0 also writes symC ------
__global__ __launch_bounds__(256) void k_prepAZY(const float* __restrict__ src,
                                                 float* __restrict__ symC,
                                                 u16* __restrict__ Ah, u16* __restrict__ Al,
                                                 u16* __restrict__ ZYh, u16* __restrict__ ZYl,
                                                 float* __restrict__ sb, int slot, int mode) {
  int xb = blockIdx.x;
  int i = xb >> 5, b = xb & 31, j = threadIdx.x;
  float trv = (mode == 0) ? 1.0f : sb[slot + b];
  float denom = trv + sb[SB_IJSUM];
  if (i == 0 && j == 0) sb[SB_DEN + b] = denom;
  size_t idx = ((size_t)b * 256 + i) * 256 + j;
  float v;
  if (mode == 0) {
    float trC = sb[SB_TRC + b];
    float vij = src[idx] / trC;
    float vji = src[((size_t)b * 256 + j) * 256 + i] / trC;
    symC[idx] = 0.5f * (vij + vji);
    v = vij;
  } else {
    v = src[idx];
  }
  if (i == j) v += sb[SB_IJ + i];
  float A = v / denom;
  u16 h = f2bf(A);
  Ah[idx] = h; Al[idx] = f2bf(A - bf2f(h));
  float zy = 0.5f * ((i == j ? 3.0f : 0.0f) - A);
  h = f2bf(zy);
  ZYh[idx] = h; ZYl[idx] = f2bf(zy - bf2f(h));
}

// ---------------- batched split-bf16 matmul — dbuf LDS, tile 32x64 --------
// C[i][j] = sum_k A[i][k]*B[j][k] (operands symmetric => A@B).
// grid 1024 (single) / 2048 (dual).
struct MMArgs {
  const u16* Ah; const u16* Al; const u16* Bh; const u16* Bl;
  u16* Oh; u16* Ol; float* Of; float* tr; int emode;
};

__global__ __launch_bounds__(256) void mm_ns(MMArgs g0, MMArgs g1,
                                             const float* __restrict__ sb) {
  int xb = blockIdx.x;
  int b = xb & 31;
  int rest = xb >> 5;
  MMArgs g = (rest < 32) ? g0 : g1;
  int tile = rest & 31;
  int tr = tile >> 2, tc = tile & 3;   // 8 row-tiles(32) x 4 col-tiles(64)
  int t = threadIdx.x, wv = t >> 6, lane = t & 63, m = lane & 15, quad = lane >> 4;
  __shared__ u16 lsAh[2][32 * 40], lsAl[2][32 * 40];
  __shared__ u16 lsBh[2][64 * 40], lsBl[2][64 * 40];
  f32x4 acc[2];
  acc[0] = (f32x4){0.f, 0.f, 0.f, 0.f};
  acc[1] = (f32x4){0.f, 0.f, 0.f, 0.f};
  int row = t >> 2, seg = t & 3;
  size_t mb = (size_t)b * 65536;
  size_t bO = mb + (size_t)(tc * 64 + row) * 256 + seg * 8;
  size_t aO = mb + (size_t)(tr * 32 + row) * 256 + seg * 8;  // row<32 only
  bool doA = row < 32;
  uint4 rBh = *(const uint4*)(g.Bh + bO);
  uint4 rBl = *(const uint4*)(g.Bl + bO);
  uint4 rAh = doA ? *(const uint4*)(g.Ah + aO) : (uint4){0, 0, 0, 0};
  uint4 rAl = doA ? *(const uint4*)(g.Al + aO) : (uint4){0, 0, 0, 0};
  int ar = (wv >> 1) * 16, bcl = (wv & 1) * 32;
  for (int ks = 0; ks < 8; ++ks) {
    int buf = ks & 1;
    int lo = row * 40 + seg * 8;
    *(uint4*)&lsBh[buf][lo] = rBh;
    *(uint4*)&lsBl[buf][lo] = rBl;
    if (doA) {
      *(uint4*)&lsAh[buf][lo] = rAh;
      *(uint4*)&lsAl[buf][lo] = rAl;
    }
    if (ks < 7) {
      int k0 = (ks + 1) * 32;
      rBh = *(const uint4*)(g.Bh + bO + k0);
      rBl = *(const uint4*)(g.Bl + bO + k0);
      if (doA) {
        rAh = *(const uint4*)(g.Ah + aO + k0);
        rAl = *(const uint4*)(g.Al + aO + k0);
      }
    }
    __syncthreads();
    bf16x8 ah = *(const bf16x8*)&lsAh[buf][(ar + m) * 40 + quad * 8];
    bf16x8 al = *(const bf16x8*)&lsAl[buf][(ar + m) * 40 + quad * 8];
    bf16x8 bh0 = *(const bf16x8*)&lsBh[buf][(bcl + m) * 40 + quad * 8];
    bf16x8 bl0 = *(const bf16x8*)&lsBl[buf][(bcl + m) * 40 + quad * 8];
    bf16x8 bh1 = *(const bf16x8*)&lsBh[buf][(bcl + 16 + m) * 40 + quad * 8];
    bf16x8 bl1 = *(const bf16x8*)&lsBl[buf][(bcl + 16 + m) * 40 + quad * 8];
    acc[0] = __builtin_amdgcn_mfma_f32_16x16x32_bf16(ah, bh0, acc[0], 0, 0, 0);
    acc[0] = __builtin_amdgcn_mfma_f32_16x16x32_bf16(ah, bl0, acc[0], 0, 0, 0);
    acc[0] = __builtin_amdgcn_mfma_f32_16x16x32_bf16(al, bh0, acc[0], 0, 0, 0);
    acc[1] = __builtin_amdgcn_mfma_f32_16x16x32_bf16(ah, bh1, acc[1], 0, 0, 0);
    acc[1] = __builtin_amdgcn_mfma_f32_16x16x32_bf16(ah, bl1, acc[1], 0, 0, 0);
    acc[1] = __builtin_amdgcn_mfma_f32_16x16x32_bf16(al, bh1, acc[1], 0, 0, 0);
  }
  float scl = 1.0f;
  if (g.emode == 2) scl = 1.0f / sqrtf(sb[SB_DEN + b]);
#pragma unroll
  for (int j = 0; j < 2; ++j)
#pragma unroll
    for (int r = 0; r < 4; ++r) {
      int R = tr * 32 + ar + quad * 4 + r;
      int Cc = tc * 64 + bcl + j * 16 + m;
      float v = acc[j][r];
      if (g.emode == 1) v = 0.5f * ((R == Cc ? 3.0f : 0.0f) - v);
      else if (g.emode == 2) v = v * scl;
      size_t oidx = mb + (size_t)R * 256 + Cc;
      if (g.emode == 3) {
        g.Of[oidx] = v;
        if (R == Cc && g.tr) atomicAdd(g.tr + b, v);
      } else {
        u16 h = f2bf(v);
        g.Oh[oidx] = h;
        g.Ol[oidx] = f2bf(v - bf2f(h));
      }
    }
}

// ---------------- SICE elementwise update, tile-symmetric ----------------
__global__ __launch_bounds__(256) void k_sice(const float* __restrict__ LLT,
                                              const float* __restrict__ P,
                                              const float* __restrict__ symC,
                                              float* __restrict__ out,
                                              float* __restrict__ sb, int slot,
                                              float dec) {
  int xb = blockIdx.x;
  int b = xb & 31, p = xb >> 5;
  const int TRt[10] = {0, 0, 0, 0, 1, 1, 1, 2, 2, 3};
  const int TCt[10] = {0, 1, 2, 3, 1, 2, 3, 2, 3, 3};
  int tr = TRt[p], tc = TCt[p];
  __shared__ float ft[64][65];
  __shared__ float ot[64][65];
  int t = threadIdx.x;
  size_t base = (size_t)b * 65536;
#pragma unroll 4
  for (int it = 0; it < 16; ++it) {
    int idx = it * 256 + t;
    int r = idx >> 6, c = idx & 63;
    size_t o = base + (size_t)(tc * 64 + r) * 256 + tr * 64 + c;
    float L = LLT[o];
    float g = symC[o] - P[o];
    float f = fmaxf(fmaxf(L, 0.f) - dec * (g + 0.07f), 0.f) -
              fmaxf(fmaxf(-L, 0.f) - dec * (-g + 0.07f), 0.f);
    ft[r][c] = f;
  }
  __syncthreads();
  float tsum = 0.f;
#pragma unroll 4
  for (int it = 0; it < 16; ++it) {
    int idx = it * 256 + t;
    int r = idx >> 6, c = idx & 63;
    size_t o = base + (size_t)(tr * 64 + r) * 256 + tc * 64 + c;
    float L = LLT[o];
    float g = symC[o] - P[o];
    float f = fmaxf(fmaxf(L, 0.f) - dec * (g + 0.07f), 0.f) -
              fmaxf(fmaxf(-L, 0.f) - dec * (-g + 0.07f), 0.f);
    float val = 0.5f * (f + ft[c][r]);
    out[o] = val;
    ot[r][c] = val;
    if (tr == tc && r == c) tsum += val;
  }
  if (tr == tc) {
    if (tsum != 0.f) atomicAdd(&sb[slot + b], tsum);
  } else {
    __syncthreads();
#pragma unroll 4
    for (int it = 0; it < 16; ++it) {
      int idx = it * 256 + t;
      int r = idx >> 6, c = idx & 63;
      size_t o = base + (size_t)(tc * 64 + r) * 256 + tr * 64 + c;
      out[o] = ot[c][r];
    }
  }
}

// ---------------- triu-vec output ----------------
__global__ __launch_bounds__(256) void k_out(const float* __restrict__ LLT,
                                             const float* __restrict__ sb,
                                             float* __restrict__ out) {
  int xb = blockIdx.x;
  int i = xb >> 5, b = xb & 31, j = threadIdx.x;
  if (j < i) return;
  float inv = 1.0f / sqrtf(sb[SB_TRL + b]);
  int tl = i * 256 - (i * (i - 1)) / 2 + (j - i);
  out[(size_t)b * 32896 + tl] = LLT[((size_t)b * 256 + i) * 256 + j] * inv;
}

extern "C" void kernel_launch(void* const* d_in, const int* in_sizes, int n_in,
                              void* d_out, int out_size, void* d_ws, size_t ws_size,
                              hipStream_t stream) {
  const float* x = (const float*)d_in[0];
  const float* w = (const float*)d_in[1];
  const float* gamma = (const float*)d_in[2];
  const float* beta = (const float*)d_in[3];
  const float* jitter = (const float*)d_in[4];
  char* ws = (char*)d_ws;

  _Float16* w_half = (_Float16*)(ws + 0);            // 1 MB
  float* sb = (float*)(ws + (1 << 20));              // 4 KB
  _Float16* y = (_Float16*)(ws + (2 << 20));         // 12.85 MB
  _Float16* yc = (_Float16*)(ws + (16 << 20));       // 13.1 MB
  char* ov = ws + (32 << 20);
  float* Craw = (float*)(ov + 0);
  float* symC = (float*)(ov + 8388608);
  float* LLTa = (float*)(ov + 16777216);
  float* P = (float*)(ov + 25165824);
  float* LLTb = (float*)(ov + 33554432);
  u16* bf[12];
  for (int i = 0; i < 12; ++i) bf[i] = (u16*)(ov + 41943040 + (size_t)i * 4194304);

  k_prep<<<2048, 256, 0, stream>>>(w, jitter, w_half, sb);
  k_conv<<<832, 256, 0, stream>>>(w_half, x, y, sb);
  k_bnapply<<<8192, 256, 0, stream>>>(y, gamma, beta, sb, yc);
  k_gram<<<1024, 256, 0, stream>>>(yc, Craw, sb);

  auto run_ns = [&](const float* src, int mode, int slot_in, float* Pout,
                    float* tr_out) {
    k_prepAZY<<<8192, 256, 0, stream>>>(src, symC, bf[0], bf[1], bf[2], bf[3], sb, slot_in, mode);
    u16 *Ah = bf[0], *Al = bf[1], *ZYh = bf[2], *ZYl = bf[3];
    u16 *Yh = bf[4], *Yl = bf[5], *Z2h = bf[6], *Z2l = bf[7];
    u16 *Th = bf[8], *Tl = bf[9], *zzh = bf[10], *zzl = bf[11];
    MMArgs m1{Ah, Al, ZYh, ZYl, Yh, Yl, nullptr, nullptr, 0};
    mm_ns<<<1024, 256, 0, stream>>>(m1, m1, sb);
    u16 *Ych = Yh, *Ycl = Yl, *Yah = Ah, *Yal = Al;
    u16 *Zch = ZYh, *Zcl = ZYl, *Zah = Z2h, *Zal = Z2l;
    for (int it = 0; it < 5; ++it) {
      MMArgs mt{Zch, Zcl, Ych, Ycl, Th, Tl, nullptr, nullptr, 1};
      mm_ns<<<1024, 256, 0, stream>>>(mt, mt, sb);
      MMArgs my{Ych, Ycl, Th, Tl, Yah, Yal, nullptr, nullptr, 0};
      MMArgs mz{Th, Tl, Zch, Zcl, Zah, Zal, nullptr, nullptr, 0};
      mm_ns<<<2048, 256, 0, stream>>>(my, mz, sb);
      std::swap(Ych, Yah); std::swap(Ycl, Yal);
      std::swap(Zch, Zah); std::swap(Zcl, Zal);
    }
    MMArgs mt6{Zch, Zcl, Ych, Ycl, Th, Tl, nullptr, nullptr, 1};
    mm_ns<<<1024, 256, 0, stream>>>(mt6, mt6, sb);
    MMArgs mz7{Th, Tl, Zch, Zcl, zzh, zzl, nullptr, nullptr, 2};
    mm_ns<<<1024, 256, 0, stream>>>(mz7, mz7, sb);
    MMArgs mzz{zzh, zzl, zzh, zzl, nullptr, nullptr, Pout, tr_out, 3};
    mm_ns<<<1024, 256, 0, stream>>>(mzz, mzz, sb);
  };

  run_ns(Craw, 0, 0, LLTa, sb + SB_TR2);   // LLT init (trace -> TR2)
  run_ns(LLTa, 1, SB_TR2, P, nullptr);     // SICE i=0
  k_sice<<<320, 256, 0, stream>>>(LLTa, P, symC, LLTb, sb, SB_TR3, 5.0f);
  run_ns(LLTb, 1, SB_TR3, P, nullptr);     // SICE i=1
  k_sice<<<320, 256, 0, stream>>>(LLTb, P, symC, LLTa, sb, SB_TRL, 2.5f);
  // SICE i=2: dec=0 -> provable no-op

  k_out<<<8192, 256, 0, stream>>>(LLTa, sb, (float*)d_out);
}

// Round 5
// 878.403 us; speedup vs baseline: 2.1254x; 1.1959x over previous
//
#include <hip/hip_runtime.h>
#include <utility>

// SICE head for MI355X (gfx950) — round 5.
// R5: (1) BN-stat atomics REMOVED from k_conv (213K device-scope atomics onto
// 2KB were serializing ~150+us across R1-R4); stats via k_stats reduction.
// (2) mm_ns drops the B-lo MFMA term (A kept split-bf16): -33% operand
// traffic (the chain is LLC-BW-bound), 4 MFMA/step, 20.5KB LDS -> 7 WG/CU.
// (3) k_prepAZY grid 1024. Batch in low 5 bits everywhere (XCD locality).

typedef unsigned short u16;
typedef __attribute__((ext_vector_type(8))) __bf16 bf16x8;
typedef __attribute__((ext_vector_type(8))) _Float16 f16x8;
typedef __attribute__((ext_vector_type(4))) float f32x4;

#define DEV __device__ __forceinline__

DEV u16 f2bf(float f) {
  unsigned x = __float_as_uint(f);
  x += 0x7fffu + ((x >> 16) & 1u);
  return (u16)(x >> 16);
}
DEV float bf2f(u16 h) { return __uint_as_float(((unsigned)h) << 16); }

// sb float-index layout
#define SB_SUM   0
#define SB_SSQ   256
#define SB_IJ    512
#define SB_TRC   768
#define SB_TR2   800
#define SB_TR3   832
#define SB_TRL   864
#define SB_DEN   896
#define SB_IJSUM 928

// ---------------- prep: w -> fp16, init sb ----------------
__global__ __launch_bounds__(256) void k_prep(const float* __restrict__ w,
                                              const float* __restrict__ jitter,
                                              _Float16* __restrict__ w_half,
                                              float* __restrict__ sb) {
  int gid = blockIdx.x * 256 + threadIdx.x;
  if (gid < 256 * 2048) w_half[gid] = (_Float16)w[gid];
  if (blockIdx.x == 0) {
    int t = threadIdx.x;
    float ij = 1e-10f + 1e-9f * jitter[t];
    sb[SB_IJ + t] = ij;
    if (t < 160) sb[SB_TRC + t] = 0.f;
    __shared__ float red[256];
    red[t] = ij; __syncthreads();
    for (int off = 128; off > 0; off >>= 1) {
      if (t < off) red[t] += red[t + off];
      __syncthreads();
    }
    if (t == 0) sb[SB_IJSUM] = red[0];
  }
}

// ---------------- conv: y[b,d,hw] = w@x (fp16 out), NO atomics ----------
// grid 832 = 26 (mt*13+ht) x 32 b. Tile 128(d) x 64(hw), BK=32, dbuf LDS.
__global__ __launch_bounds__(256) void k_conv(const _Float16* __restrict__ w_half,
                                              const float* __restrict__ x,
                                              _Float16* __restrict__ y) {
  int xb = blockIdx.x;
  int b = xb & 31;
  int rest = xb >> 5;              // 0..25
  int mt = rest / 13, ht = rest % 13;
  int hw0 = ht * 64;
  int t = threadIdx.x;
  int wv = t >> 6, lane = t & 63, m = lane & 15, quad = lane >> 4;
  __shared__ _Float16 lsA[2][128 * 40];
  __shared__ _Float16 lsB[2][64 * 40];
  f32x4 acc[4][2];
#pragma unroll
  for (int i = 0; i < 4; ++i)
#pragma unroll
    for (int j = 0; j < 2; ++j) acc[i][j] = (f32x4){0.f, 0.f, 0.f, 0.f};
  int rowA = t & 127, halfA = t >> 7;
  const _Float16* wp = w_half + ((size_t)(mt * 128 + rowA)) * 2048 + halfA * 16;
  int hwB = t & 63, cg = t >> 6;
  bool okB = (hw0 + hwB) < 784;
  const float* xp = x + ((size_t)b * 2048 + cg * 8) * 784 + hw0 + hwB;
  uint4 ra0, ra1;
  float rb[8];
  ra0 = *(const uint4*)(wp);
  ra1 = *(const uint4*)(wp + 8);
#pragma unroll
  for (int j = 0; j < 8; ++j) rb[j] = okB ? xp[(size_t)j * 784] : 0.f;
  int wr = (wv >> 1) * 64, wc = (wv & 1) * 32;
  for (int kc = 0; kc < 64; ++kc) {
    int buf = kc & 1;
    int loA = rowA * 40 + halfA * 16;
    *(uint4*)&lsA[buf][loA] = ra0;
    *(uint4*)&lsA[buf][loA + 8] = ra1;
    {
      union { f16x8 h; uint4 u; } pk;
#pragma unroll
      for (int j = 0; j < 8; ++j) pk.h[j] = (_Float16)rb[j];
      *(uint4*)&lsB[buf][hwB * 40 + cg * 8] = pk.u;
    }
    if (kc < 63) {
      int k0 = (kc + 1) * 32;
      ra0 = *(const uint4*)(wp + k0);
      ra1 = *(const uint4*)(wp + k0 + 8);
#pragma unroll
      for (int j = 0; j < 8; ++j)
        rb[j] = okB ? xp[((size_t)k0 + j) * 784] : 0.f;
    }
    __syncthreads();
    f16x8 af[4], bfg[2];
#pragma unroll
    for (int i = 0; i < 4; ++i)
      af[i] = *(const f16x8*)&lsA[buf][(wr + i * 16 + m) * 40 + quad * 8];
#pragma unroll
    for (int j = 0; j < 2; ++j)
      bfg[j] = *(const f16x8*)&lsB[buf][(wc + j * 16 + m) * 40 + quad * 8];
#pragma unroll
    for (int i = 0; i < 4; ++i)
#pragma unroll
      for (int j = 0; j < 2; ++j)
        acc[i][j] = __builtin_amdgcn_mfma_f32_16x16x32_f16(af[i], bfg[j], acc[i][j], 0, 0, 0);
  }
#pragma unroll
  for (int i = 0; i < 4; ++i)
#pragma unroll
    for (int j = 0; j < 2; ++j)
#pragma unroll
      for (int r = 0; r < 4; ++r) {
        int R = mt * 128 + wr + i * 16 + quad * 4 + r;
        int hwc = hw0 + wc + j * 16 + m;
        if (hwc < 784) y[((size_t)b * 256 + R) * 784 + hwc] = (_Float16)acc[i][j][r];
      }
}

// ---------------- BN stats from y: grid 256 (one block per d) ------------
__global__ __launch_bounds__(256) void k_stats(const _Float16* __restrict__ y,
                                               float* __restrict__ sb) {
  int d = blockIdx.x, t = threadIdx.x;
  float s = 0.f, q = 0.f;
  if (t < 196) {
    for (int b = 0; b < 32; ++b) {
      const _Float16* row = y + ((size_t)b * 256 + d) * 784;
      union { uint2 u; _Float16 h[4]; } v;
      v.u = *(const uint2*)(row + t * 4);
#pragma unroll
      for (int k = 0; k < 4; ++k) {
        float f = (float)v.h[k];
        s += f; q += f * f;
      }
    }
  }
  __shared__ float rs[256], rq[256];
  rs[t] = s; rq[t] = q; __syncthreads();
  for (int off = 128; off > 0; off >>= 1) {
    if (t < off) { rs[t] += rs[t + off]; rq[t] += rq[t + off]; }
    __syncthreads();
  }
  if (t == 0) { sb[SB_SUM + d] = rs[0]; sb[SB_SSQ + d] = rq[0]; }
}

// ---------------- BN finalize+apply + relu + row-center -> yc fp16 --------
__global__ __launch_bounds__(256) void k_bnapply(const _Float16* __restrict__ y,
                                                 const float* __restrict__ gamma,
                                                 const float* __restrict__ beta,
                                                 const float* __restrict__ sb,
                                                 _Float16* __restrict__ yc) {
  int xb = blockIdx.x;
  int d = xb >> 5, b = xb & 31, t = threadIdx.x;
  float mu = sb[SB_SUM + d] * (1.0f / 25088.0f);
  float var = sb[SB_SSQ + d] * (1.0f / 25088.0f) - mu * mu;
  float sc = gamma[d] / sqrtf(var + 1e-5f);
  float sh = beta[d] - mu * sc;
  const _Float16* row = y + ((size_t)b * 256 + d) * 784;
  float v[4];
  float s = 0.f;
#pragma unroll
  for (int i = 0; i < 4; ++i) {
    int idx = t + i * 256;
    float u = 0.f;
    if (idx < 784) u = fmaxf((float)row[idx] * sc + sh, 0.f);
    v[i] = u; s += u;
  }
  __shared__ float red[256];
  red[t] = s; __syncthreads();
  for (int off = 128; off > 0; off >>= 1) {
    if (t < off) red[t] += red[t + off];
    __syncthreads();
  }
  float mean = red[0] * (1.0f / 784.0f);
  _Float16* out = yc + ((size_t)b * 256 + d) * 800;
#pragma unroll
  for (int i = 0; i < 4; ++i) {
    int idx = t + i * 256;
    if (idx < 784) out[idx] = (_Float16)(v[i] - mean);
  }
  if (t < 16) out[784 + t] = (_Float16)0.f;
}

// ---------------- gram: C = yc@yc^T/784 — dbuf LDS, tile 32x64 -----------
__global__ __launch_bounds__(256) void k_gram(const _Float16* __restrict__ yc,
                                              float* __restrict__ C,
                                              float* __restrict__ sb) {
  int xb = blockIdx.x;
  int b = xb & 31, rest = xb >> 5;
  int tr = rest >> 2, tc = rest & 3;
  int t = threadIdx.x, wv = t >> 6, lane = t & 63, m = lane & 15, quad = lane >> 4;
  __shared__ _Float16 lsA[2][32 * 40];
  __shared__ _Float16 lsB[2][64 * 40];
  f32x4 acc[2];
  acc[0] = (f32x4){0.f, 0.f, 0.f, 0.f};
  acc[1] = (f32x4){0.f, 0.f, 0.f, 0.f};
  int row = t >> 2, seg = t & 3;
  const _Float16* base = yc + (size_t)b * 256 * 800;
  const _Float16* Bp = base + (size_t)(tc * 64 + row) * 800 + seg * 8;
  const _Float16* Ap = base + (size_t)(tr * 32 + row) * 800 + seg * 8;
  bool doA = row < 32;
  uint4 rB = *(const uint4*)(Bp);
  uint4 rA = doA ? *(const uint4*)(Ap) : (uint4){0, 0, 0, 0};
  int ar = (wv >> 1) * 16, bcl = (wv & 1) * 32;
  for (int ks = 0; ks < 25; ++ks) {
    int buf = ks & 1;
    int lo = row * 40 + seg * 8;
    *(uint4*)&lsB[buf][lo] = rB;
    if (doA) *(uint4*)&lsA[buf][lo] = rA;
    if (ks < 24) {
      int k0 = (ks + 1) * 32;
      rB = *(const uint4*)(Bp + k0);
      if (doA) rA = *(const uint4*)(Ap + k0);
    }
    __syncthreads();
    f16x8 a0 = *(const f16x8*)&lsA[buf][(ar + m) * 40 + quad * 8];
    f16x8 b0 = *(const f16x8*)&lsB[buf][(bcl + m) * 40 + quad * 8];
    f16x8 b1 = *(const f16x8*)&lsB[buf][(bcl + 16 + m) * 40 + quad * 8];
    acc[0] = __builtin_amdgcn_mfma_f32_16x16x32_f16(a0, b0, acc[0], 0, 0, 0);
    acc[1] = __builtin_amdgcn_mfma_f32_16x16x32_f16(a0, b1, acc[1], 0, 0, 0);
  }
  const float inv = 1.0f / 784.0f;
#pragma unroll
  for (int j = 0; j < 2; ++j)
#pragma unroll
    for (int r = 0; r < 4; ++r) {
      int R = tr * 32 + ar + quad * 4 + r;
      int Cc = tc * 64 + bcl + j * 16 + m;
      float v = acc[j][r] * inv;
      C[((size_t)b * 256 + R) * 256 + Cc] = v;
      if (R == Cc) atomicAdd(&sb[SB_TRC + b], v);
    }
}

// ---------------- prep A and ZY (split bf16); mode0 also writes symC ------
// grid 1024 = 32 i-groups x 32 b; 8 rows per block.
__global__ __launch_bounds__(256) void k_prepAZY(const float* __restrict__ src,
                                                 float* __restrict__ symC,
                                                 u16* __restrict__ Ah, u16* __restrict__ Al,
                                                 u16* __restrict__ ZYh, u16* __restrict__ ZYl,
                                                 float* __restrict__ sb, int slot, int mode) {
  int xb = blockIdx.x;
  int ig = xb >> 5, b = xb & 31, j = threadIdx.x;
  float trv = (mode == 0) ? 1.0f : sb[slot + b];
  float denom = trv + sb[SB_IJSUM];
  if (ig == 0 && j == 0) sb[SB_DEN + b] = denom;
  float trC = (mode == 0) ? sb[SB_TRC + b] : 1.0f;
#pragma unroll
  for (int ii = 0; ii < 8; ++ii) {
    int i = ig * 8 + ii;
    size_t idx = ((size_t)b * 256 + i) * 256 + j;
    float v;
    if (mode == 0) {
      float vij = src[idx] / trC;
      float vji = src[((size_t)b * 256 + j) * 256 + i] / trC;
      symC[idx] = 0.5f * (vij + vji);
      v = vij;
    } else {
      v = src[idx];
    }
    if (i == j) v += sb[SB_IJ + i];
    float A = v / denom;
    u16 h = f2bf(A);
    Ah[idx] = h; Al[idx] = f2bf(A - bf2f(h));
    float zy = 0.5f * ((i == j ? 3.0f : 0.0f) - A);
    h = f2bf(zy);
    ZYh[idx] = h; ZYl[idx] = f2bf(zy - bf2f(h));
  }
}

// ---------------- batched matmul C = (Ah+Al)@Bh — dbuf LDS, tile 32x64 ----
// operands symmetric => row-row dot == A@B. B-lo term dropped (B ~ bf16).
struct MMArgs {
  const u16* Ah; const u16* Al; const u16* Bh;
  u16* Oh; u16* Ol; float* Of; float* tr; int emode;
};

__global__ __launch_bounds__(256) void mm_ns(MMArgs g0, MMArgs g1,
                                             const float* __restrict__ sb) {
  int xb = blockIdx.x;
  int b = xb & 31;
  int rest = xb >> 5;
  MMArgs g = (rest < 32) ? g0 : g1;
  int tile = rest & 31;
  int tr = tile >> 2, tc = tile & 3;
  int t = threadIdx.x, wv = t >> 6, lane = t & 63, m = lane & 15, quad = lane >> 4;
  __shared__ u16 lsAh[2][32 * 40], lsAl[2][32 * 40];
  __shared__ u16 lsBh[2][64 * 40];
  f32x4 acc[2];
  acc[0] = (f32x4){0.f, 0.f, 0.f, 0.f};
  acc[1] = (f32x4){0.f, 0.f, 0.f, 0.f};
  int row = t >> 2, seg = t & 3;
  size_t mb = (size_t)b * 65536;
  size_t bO = mb + (size_t)(tc * 64 + row) * 256 + seg * 8;
  size_t aO = mb + (size_t)(tr * 32 + row) * 256 + seg * 8;
  bool doA = row < 32;
  uint4 rBh = *(const uint4*)(g.Bh + bO);
  uint4 rAh = doA ? *(const uint4*)(g.Ah + aO) : (uint4){0, 0, 0, 0};
  uint4 rAl = doA ? *(const uint4*)(g.Al + aO) : (uint4){0, 0, 0, 0};
  int ar = (wv >> 1) * 16, bcl = (wv & 1) * 32;
  for (int ks = 0; ks < 8; ++ks) {
    int buf = ks & 1;
    int lo = row * 40 + seg * 8;
    *(uint4*)&lsBh[buf][lo] = rBh;
    if (doA) {
      *(uint4*)&lsAh[buf][lo] = rAh;
      *(uint4*)&lsAl[buf][lo] = rAl;
    }
    if (ks < 7) {
      int k0 = (ks + 1) * 32;
      rBh = *(const uint4*)(g.Bh + bO + k0);
      if (doA) {
        rAh = *(const uint4*)(g.Ah + aO + k0);
        rAl = *(const uint4*)(g.Al + aO + k0);
      }
    }
    __syncthreads();
    bf16x8 ah = *(const bf16x8*)&lsAh[buf][(ar + m) * 40 + quad * 8];
    bf16x8 al = *(const bf16x8*)&lsAl[buf][(ar + m) * 40 + quad * 8];
    bf16x8 bh0 = *(const bf16x8*)&lsBh[buf][(bcl + m) * 40 + quad * 8];
    bf16x8 bh1 = *(const bf16x8*)&lsBh[buf][(bcl + 16 + m) * 40 + quad * 8];
    acc[0] = __builtin_amdgcn_mfma_f32_16x16x32_bf16(ah, bh0, acc[0], 0, 0, 0);
    acc[0] = __builtin_amdgcn_mfma_f32_16x16x32_bf16(al, bh0, acc[0], 0, 0, 0);
    acc[1] = __builtin_amdgcn_mfma_f32_16x16x32_bf16(ah, bh1, acc[1], 0, 0, 0);
    acc[1] = __builtin_amdgcn_mfma_f32_16x16x32_bf16(al, bh1, acc[1], 0, 0, 0);
  }
  float scl = 1.0f;
  if (g.emode == 2) scl = 1.0f / sqrtf(sb[SB_DEN + b]);
#pragma unroll
  for (int j = 0; j < 2; ++j)
#pragma unroll
    for (int r = 0; r < 4; ++r) {
      int R = tr * 32 + ar + quad * 4 + r;
      int Cc = tc * 64 + bcl + j * 16 + m;
      float v = acc[j][r];
      if (g.emode == 1) v = 0.5f * ((R == Cc ? 3.0f : 0.0f) - v);
      else if (g.emode == 2) v = v * scl;
      size_t oidx = mb + (size_t)R * 256 + Cc;
      if (g.emode == 3) {
        g.Of[oidx] = v;
        if (R == Cc && g.tr) atomicAdd(g.tr + b, v);
      } else {
        u16 h = f2bf(v);
        g.Oh[oidx] = h;
        g.Ol[oidx] = f2bf(v - bf2f(h));
      }
    }
}

// ---------------- SICE elementwise update, tile-symmetric ----------------
__global__ __launch_bounds__(256) void k_sice(const float* __restrict__ LLT,
                                              const float* __restrict__ P,
                                              const float* __restrict__ symC,
                                              float* __restrict__ out,
                                              float* __restrict__ sb, int slot,
                                              float dec) {
  int xb = blockIdx.x;
  int b = xb & 31, p = xb >> 5;
  const int TRt[10] = {0, 0, 0, 0, 1, 1, 1, 2, 2, 3};
  const int TCt[10] = {0, 1, 2, 3, 1, 2, 3, 2, 3, 3};
  int tr = TRt[p], tc = TCt[p];
  __shared__ float ft[64][65];
  __shared__ float ot[64][65];
  int t = threadIdx.x;
  size_t base = (size_t)b * 65536;
#pragma unroll 4
  for (int it = 0; it < 16; ++it) {
    int idx = it * 256 + t;
    int r = idx >> 6, c = idx & 63;
    size_t o = base + (size_t)(tc * 64 + r) * 256 + tr * 64 + c;
    float L = LLT[o];
    float g = symC[o] - P[o];
    float f = fmaxf(fmaxf(L, 0.f) - dec * (g + 0.07f), 0.f) -
              fmaxf(fmaxf(-L, 0.f) - dec * (-g + 0.07f), 0.f);
    ft[r][c] = f;
  }
  __syncthreads();
  float tsum = 0.f;
#pragma unroll 4
  for (int it = 0; it < 16; ++it) {
    int idx = it * 256 + t;
    int r = idx >> 6, c = idx & 63;
    size_t o = base + (size_t)(tr * 64 + r) * 256 + tc * 64 + c;
    float L = LLT[o];
    float g = symC[o] - P[o];
    float f = fmaxf(fmaxf(L, 0.f) - dec * (g + 0.07f), 0.f) -
              fmaxf(fmaxf(-L, 0.f) - dec * (-g + 0.07f), 0.f);
    float val = 0.5f * (f + ft[c][r]);
    out[o] = val;
    ot[r][c] = val;
    if (tr == tc && r == c) tsum += val;
  }
  if (tr == tc) {
    if (tsum != 0.f) atomicAdd(&sb[slot + b], tsum);
  } else {
    __syncthreads();
#pragma unroll 4
    for (int it = 0; it < 16; ++it) {
      int idx = it * 256 + t;
      int r = idx >> 6, c = idx & 63;
      size_t o = base + (size_t)(tc * 64 + r) * 256 + tr * 64 + c;
      out[o] = ot[c][r];
    }
  }
}

// ---------------- triu-vec output ----------------
__global__ __launch_bounds__(256) void k_out(const float* __restrict__ LLT,
                                             const float* __restrict__ sb,
                                             float* __restrict__ out) {
  int xb = blockIdx.x;
  int i = xb >> 5, b = xb & 31, j = threadIdx.x;
  if (j < i) return;
  float inv = 1.0f / sqrtf(sb[SB_TRL + b]);
  int tl = i * 256 - (i * (i - 1)) / 2 + (j - i);
  out[(size_t)b * 32896 + tl] = LLT[((size_t)b * 256 + i) * 256 + j] * inv;
}

extern "C" void kernel_launch(void* const* d_in, const int* in_sizes, int n_in,
                              void* d_out, int out_size, void* d_ws, size_t ws_size,
                              hipStream_t stream) {
  const float* x = (const float*)d_in[0];
  const float* w = (const float*)d_in[1];
  const float* gamma = (const float*)d_in[2];
  const float* beta = (const float*)d_in[3];
  const float* jitter = (const float*)d_in[4];
  char* ws = (char*)d_ws;

  _Float16* w_half = (_Float16*)(ws + 0);            // 1 MB
  float* sb = (float*)(ws + (1 << 20));              // 4 KB
  _Float16* y = (_Float16*)(ws + (2 << 20));         // 12.85 MB
  _Float16* yc = (_Float16*)(ws + (16 << 20));       // 13.1 MB
  char* ov = ws + (32 << 20);
  float* Craw = (float*)(ov + 0);
  float* symC = (float*)(ov + 8388608);
  float* LLTa = (float*)(ov + 16777216);
  float* P = (float*)(ov + 25165824);
  float* LLTb = (float*)(ov + 33554432);
  u16* bf[12];
  for (int i = 0; i < 12; ++i) bf[i] = (u16*)(ov + 41943040 + (size_t)i * 4194304);

  k_prep<<<2048, 256, 0, stream>>>(w, jitter, w_half, sb);
  k_conv<<<832, 256, 0, stream>>>(w_half, x, y);
  k_stats<<<256, 256, 0, stream>>>(y, sb);
  k_bnapply<<<8192, 256, 0, stream>>>(y, gamma, beta, sb, yc);
  k_gram<<<1024, 256, 0, stream>>>(yc, Craw, sb);

  auto run_ns = [&](const float* src, int mode, int slot_in, float* Pout,
                    float* tr_out) {
    k_prepAZY<<<1024, 256, 0, stream>>>(src, symC, bf[0], bf[1], bf[2], bf[3], sb, slot_in, mode);
    u16 *Ah = bf[0], *Al = bf[1], *ZYh = bf[2], *ZYl = bf[3];
    u16 *Yh = bf[4], *Yl = bf[5], *Z2h = bf[6], *Z2l = bf[7];
    u16 *Th = bf[8], *Tl = bf[9], *zzh = bf[10], *zzl = bf[11];
    MMArgs m1{Ah, Al, ZYh, Yh, Yl, nullptr, nullptr, 0};       // Y = A@ZY
    mm_ns<<<1024, 256, 0, stream>>>(m1, m1, sb);
    u16 *Ych = Yh, *Ycl = Yl, *Yah = Ah, *Yal = Al;
    u16 *Zch = ZYh, *Zcl = ZYl, *Zah = Z2h, *Zal = Z2l;
    for (int it = 0; it < 5; ++it) {
      MMArgs mt{Zch, Zcl, Ych, Th, Tl, nullptr, nullptr, 1};   // T = 0.5(3I-Z@Y)
      mm_ns<<<1024, 256, 0, stream>>>(mt, mt, sb);
      MMArgs my{Ych, Ycl, Th, Yah, Yal, nullptr, nullptr, 0};  // Y' = Y@T
      MMArgs mz{Th, Tl, Zch, Zah, Zal, nullptr, nullptr, 0};   // Z' = T@Z
      mm_ns<<<2048, 256, 0, stream>>>(my, mz, sb);
      std::swap(Ych, Yah); std::swap(Ycl, Yal);
      std::swap(Zch, Zah); std::swap(Zcl, Zal);
    }
    MMArgs mt6{Zch, Zcl, Ych, Th, Tl, nullptr, nullptr, 1};
    mm_ns<<<1024, 256, 0, stream>>>(mt6, mt6, sb);
    MMArgs mz7{Th, Tl, Zch, zzh, zzl, nullptr, nullptr, 2};    // zz = T@Z * rsqrt
    mm_ns<<<1024, 256, 0, stream>>>(mz7, mz7, sb);
    MMArgs mzz{zzh, zzl, zzh, nullptr, nullptr, Pout, tr_out, 3};  // P = zz@zz
    mm_ns<<<1024, 256, 0, stream>>>(mzz, mzz, sb);
  };

  run_ns(Craw, 0, 0, LLTa, sb + SB_TR2);   // LLT init (trace -> TR2)
  run_ns(LLTa, 1, SB_TR2, P, nullptr);     // SICE i=0
  k_sice<<<320, 256, 0, stream>>>(LLTa, P, symC, LLTb, sb, SB_TR3, 5.0f);
  run_ns(LLTb, 1, SB_TR3, P, nullptr);     // SICE i=1
  k_sice<<<320, 256, 0, stream>>>(LLTb, P, symC, LLTa, sb, SB_TRL, 2.5f);
  // SICE i=2: dec=0 -> provable no-op

  k_out<<<8192, 256, 0, stream>>>(LLTa, sb, (float*)d_out);
}